// Round 9
// baseline (859.387 us; speedup 1.0000x reference)
//
#include <hip/hip_runtime.h>
#include <hip/hip_bf16.h>
#include <cstdint>

#define NB   8192
#define NE   16
#define NHI  1024
#define NHO  1024
#define KSEL 4

#define BM 128
#define BN 128
#define BK 64
#define LDA 72   // padded bf16 leading dim (144 B) to stagger LDS banks

typedef float f4_t  __attribute__((ext_vector_type(4)));
typedef short bf8_t __attribute__((ext_vector_type(8)));  // 8 bf16 in 4 VGPRs

static __device__ __forceinline__ uint32_t f2b(float f) {
    uint32_t u = __builtin_bit_cast(uint32_t, f);
    return (u + 0x7fffu + ((u >> 16) & 1u)) >> 16;  // RNE fp32->bf16
}

// ---------------- router: logits (fp32), top-4, probs, lists ----------------
__global__ __launch_bounds__(256) void k_router(
    const float* __restrict__ x, const float* __restrict__ W_r,
    const float* __restrict__ b_r,
    int* __restrict__ cnt, float* __restrict__ psum, int* __restrict__ selc,
    int* __restrict__ tlist, float* __restrict__ plist)
{
    const int lane  = threadIdx.x & 63;
    const int b     = blockIdx.x * 4 + (threadIdx.x >> 6);   // one wave per token
    const int e     = lane & 15;
    const int chunk = lane >> 4;                              // 4 chunks of 256

    const float4* x4 = (const float4*)(x + (size_t)b * NHI + chunk * 256);
    const float4* w4 = (const float4*)(W_r + (size_t)e * NHI + chunk * 256);
    float acc = 0.f;
#pragma unroll 16
    for (int i = 0; i < 64; ++i) {
        float4 a = x4[i], w = w4[i];
        acc += a.x * w.x + a.y * w.y + a.z * w.z + a.w * w.w;
    }
    acc += __shfl_xor(acc, 16);
    acc += __shfl_xor(acc, 32);          // all lanes with same (lane&15) now equal
    float v  = acc + b_r[e];
    int  idx = e;

    float pv[KSEL]; int pe[KSEL];
#pragma unroll
    for (int k = 0; k < KSEL; ++k) {
        float mv = v; int mi = idx;
#pragma unroll
        for (int s = 8; s >= 1; s >>= 1) {   // reduce among 16 experts (dup groups agree)
            float ov = __shfl_xor(mv, s);
            int   oi = __shfl_xor(mi, s);
            if (ov > mv || (ov == mv && oi < mi)) { mv = ov; mi = oi; }
        }
        pv[k] = mv; pe[k] = mi;
        if (idx == mi) v = -3.0e38f;         // remove winner for next round
    }
    // softmax over top-4 (masked logits' exp underflows to exactly 0)
    float m0 = pv[0];
    float ex[KSEL]; float s = 0.f;
#pragma unroll
    for (int k = 0; k < KSEL; ++k) { ex[k] = expf(pv[k] - m0); s += ex[k]; }
    float inv = 1.f / s;

    if (lane == 0) {
        atomicAdd(&selc[pe[0]], 1);          // top-1 (argmax, first-index ties)
#pragma unroll
        for (int k = 0; k < KSEL; ++k) {
            float p = ex[k] * inv;
            atomicAdd(&psum[pe[k]], p);
            int pos = atomicAdd(&cnt[pe[k]], 1);
            tlist[pe[k] * NB + pos] = b;
            plist[pe[k] * NB + pos] = p;
        }
    }
}

// ---------------- grouped gathered GEMM: out += p * (x @ W_e^T + b_e) ----------------
__global__ __launch_bounds__(256) void k_gemm(
    const float* __restrict__ x, const float* __restrict__ W_e,
    const float* __restrict__ b_e, const int* __restrict__ cnt,
    const int* __restrict__ tlist, const float* __restrict__ plist,
    float* __restrict__ out)
{
    const int e     = blockIdx.z;
    const int count = cnt[e];
    const int mt    = blockIdx.y;
    if (mt * BM >= count) return;
    const int nt   = blockIdx.x;
    const int tid  = threadIdx.x;
    const int lane = tid & 63;
    const int w    = tid >> 6;
    const int wm = w >> 1, wn = w & 1;     // 2x2 waves, 64x64 each
    const int fr = lane & 15, fq = lane >> 4;

    __shared__ short As[BM][LDA];
    __shared__ short Bs[BM][LDA];

    const int col4 = tid & 15;   // which float4 along K
    const int r0   = tid >> 4;   // 0..15
    const int* tl  = tlist + e * NB;

    int tokr[8];
#pragma unroll
    for (int rr = 0; rr < 8; ++rr) {
        int g = mt * BM + r0 + rr * 16;
        tokr[rr] = tl[min(g, count - 1)];   // clamp: rows >= count are computed but never stored
    }
    const float* wb = W_e + (size_t)e * NHO * NHI + (size_t)(nt * BN) * NHI;

    f4_t acc[4][4];
#pragma unroll
    for (int i = 0; i < 4; ++i)
#pragma unroll
        for (int j = 0; j < 4; ++j) acc[i][j] = {0.f, 0.f, 0.f, 0.f};

    for (int k0 = 0; k0 < NHI; k0 += BK) {
#pragma unroll
        for (int rr = 0; rr < 8; ++rr) {
            int r = r0 + rr * 16;
            float4 av = *(const float4*)(x + (size_t)tokr[rr] * NHI + k0 + col4 * 4);
            uint2 ap; ap.x = f2b(av.x) | (f2b(av.y) << 16); ap.y = f2b(av.z) | (f2b(av.w) << 16);
            *(uint2*)&As[r][col4 * 4] = ap;
            float4 wv = *(const float4*)(wb + (size_t)r * NHI + k0 + col4 * 4);
            uint2 wp; wp.x = f2b(wv.x) | (f2b(wv.y) << 16); wp.y = f2b(wv.z) | (f2b(wv.w) << 16);
            *(uint2*)&Bs[r][col4 * 4] = wp;
        }
        __syncthreads();
#pragma unroll
        for (int kk = 0; kk < 2; ++kk) {
            bf8_t af[4], bfr[4];
#pragma unroll
            for (int m = 0; m < 4; ++m)
                af[m] = *(const bf8_t*)&As[wm * 64 + m * 16 + fr][kk * 32 + fq * 8];
#pragma unroll
            for (int n = 0; n < 4; ++n)
                bfr[n] = *(const bf8_t*)&Bs[wn * 64 + n * 16 + fr][kk * 32 + fq * 8];
#pragma unroll
            for (int m = 0; m < 4; ++m)
#pragma unroll
                for (int n = 0; n < 4; ++n)
                    acc[m][n] = __builtin_amdgcn_mfma_f32_16x16x32_bf16(af[m], bfr[n], acc[m][n], 0, 0, 0);
        }
        __syncthreads();
    }

    // epilogue: out[tok, o] += p * (acc + b_e[e, o])
    const float* be = b_e + e * NHO;
    float bias[4];
#pragma unroll
    for (int n = 0; n < 4; ++n) bias[n] = be[nt * BN + wn * 64 + n * 16 + fr];
    const float* pl = plist + e * NB;
#pragma unroll
    for (int m = 0; m < 4; ++m) {
#pragma unroll
        for (int ri = 0; ri < 4; ++ri) {
            int g = mt * BM + wm * 64 + m * 16 + fq * 4 + ri;
            if (g < count) {
                int tok = tl[g];
                float p = pl[g];
                float* orow = out + (size_t)tok * NHO + nt * BN + wn * 64;
#pragma unroll
                for (int n = 0; n < 4; ++n)
                    atomicAdd(orow + n * 16 + fr, p * (acc[m][n][ri] + bias[n]));
            }
        }
    }
}

// ---------------- finalize: frac_prob + load balance loss ----------------
__global__ void k_fin(const int* __restrict__ selc, const float* __restrict__ psum,
                      float* __restrict__ tail)
{
    int t = threadIdx.x;
    if (t < NE) tail[t] = psum[t] * (1.f / NB);
    if (t == 0) {
        float l = 0.f;
        for (int e2 = 0; e2 < NE; ++e2)
            l += ((float)selc[e2] * (1.f / NB)) * (psum[e2] * (1.f / NB));
        tail[NE] = (float)NE * l;
    }
}

extern "C" void kernel_launch(void* const* d_in, const int* in_sizes, int n_in,
                              void* d_out, int out_size, void* d_ws, size_t ws_size,
                              hipStream_t stream)
{
    const float* x   = (const float*)d_in[0];
    const float* W_e = (const float*)d_in[1];
    const float* b_e = (const float*)d_in[2];
    const float* W_r = (const float*)d_in[3];
    const float* b_r = (const float*)d_in[4];
    float* out = (float*)d_out;

    char* ws = (char*)d_ws;
    int*   cnt   = (int*)(ws);
    int*   selc  = (int*)(ws + 64);
    float* psum  = (float*)(ws + 128);
    int*   tlist = (int*)(ws + 256);
    float* plist = (float*)(ws + 256 + sizeof(int) * (size_t)NE * NB);

    hipMemsetAsync(d_out, 0, sizeof(float) * (size_t)NB * NHO, stream);
    hipMemsetAsync(ws, 0, 256, stream);
    k_router<<<dim3(NB / 4), dim3(256), 0, stream>>>(x, W_r, b_r, cnt, psum, selc, tlist, plist);
    k_gemm<<<dim3(NHO / BN, NB / BM, NE), dim3(256), 0, stream>>>(x, W_e, b_e, cnt, tlist, plist, out);
    k_fin<<<dim3(1), dim3(64), 0, stream>>>(selc, psum, out + (size_t)NB * NHO);
}

// Round 14
// 482.969 us; speedup vs baseline: 1.7794x; 1.7794x over previous
//
#include <hip/hip_runtime.h>
#include <hip/hip_bf16.h>
#include <cstdint>

#define NB   8192
#define NE   16
#define NHI  1024
#define NHO  1024
#define KSEL 4

#define BM 128
#define BN 128
#define BK 64
#define LDA 72   // padded bf16 leading dim (144 B)

typedef float f4_t  __attribute__((ext_vector_type(4)));
typedef short bf8_t __attribute__((ext_vector_type(8)));  // 8 bf16 in 4 VGPRs

static __device__ __forceinline__ uint32_t f2b(float f) {
    uint32_t u = __builtin_bit_cast(uint32_t, f);
    return (u + 0x7fffu + ((u >> 16) & 1u)) >> 16;  // RNE fp32->bf16
}

// ---------------- fp32 -> bf16 bulk convert (8 elems/thread) ----------------
__global__ __launch_bounds__(256) void k_cvt(const float* __restrict__ src,
                                             uint32_t* __restrict__ dst, int n8)
{
    int i = blockIdx.x * 256 + threadIdx.x;
    if (i >= n8) return;
    const float4* s4 = (const float4*)src;
    float4 a = s4[2 * i], b = s4[2 * i + 1];
    uint4 o;
    o.x = f2b(a.x) | (f2b(a.y) << 16);
    o.y = f2b(a.z) | (f2b(a.w) << 16);
    o.z = f2b(b.x) | (f2b(b.y) << 16);
    o.w = f2b(b.z) | (f2b(b.w) << 16);
    ((uint4*)dst)[i] = o;
}

// ---------------- router: W_r^T staged in LDS, thread = (token, expert) ----------------
__global__ __launch_bounds__(256) void k_router(
    const float* __restrict__ x, const float* __restrict__ W_r,
    const float* __restrict__ b_r,
    int* __restrict__ cnt, float* __restrict__ psum, int* __restrict__ selc,
    int* __restrict__ tlist, float* __restrict__ plist)
{
    __shared__ float wt[NHI][NE];              // transposed W_r, exactly 64 KB
    const int tid = threadIdx.x;
#pragma unroll
    for (int i = 0; i < 16; ++i) {             // stage 16 KB/iter, linear read, scatter write
        int j = tid + 256 * i;                 // float4 index into W_r
        float4 wv = ((const float4*)W_r)[j];
        int e = j >> 8;                        // which expert row
        int k = (j & 255) * 4;
        wt[k][e] = wv.x; wt[k + 1][e] = wv.y; wt[k + 2][e] = wv.z; wt[k + 3][e] = wv.w;
    }
    __syncthreads();

    const int e = tid & 15, t = tid >> 4;      // 16 tokens per block
    const int b = blockIdx.x * 16 + t;
    const float4* x4 = (const float4*)(x + (size_t)b * NHI);
    float a0 = 0.f, a1 = 0.f, a2 = 0.f, a3 = 0.f;
#pragma unroll 4
    for (int i = 0; i < 256; ++i) {
        float4 xv = x4[i];                     // broadcast across the 16-lane group
        int k = i * 4;
        a0 += xv.x * wt[k][e];
        a1 += xv.y * wt[k + 1][e];
        a2 += xv.z * wt[k + 2][e];
        a3 += xv.w * wt[k + 3][e];
    }
    float v  = ((a0 + a1) + (a2 + a3)) + b_r[e];
    int  idx = e;

    float pv[KSEL]; int pe[KSEL];
#pragma unroll
    for (int kk = 0; kk < KSEL; ++kk) {
        float mv = v; int mi = idx;
#pragma unroll
        for (int s = 8; s >= 1; s >>= 1) {     // argmax over the 16-lane token group
            float ov = __shfl_xor(mv, s);
            int   oi = __shfl_xor(mi, s);
            if (ov > mv || (ov == mv && oi < mi)) { mv = ov; mi = oi; }
        }
        pv[kk] = mv; pe[kk] = mi;
        if (idx == mi) v = -3.0e38f;           // remove winner
    }
    float m0 = pv[0], s = 0.f, ex[KSEL];
#pragma unroll
    for (int kk = 0; kk < KSEL; ++kk) { ex[kk] = expf(pv[kk] - m0); s += ex[kk]; }
    float inv = 1.f / s;

    if (e == 0) {
        atomicAdd(&selc[pe[0]], 1);            // top-1 (first-index ties)
#pragma unroll
        for (int kk = 0; kk < KSEL; ++kk) {
            float p = ex[kk] * inv;
            atomicAdd(&psum[pe[kk]], p);
            int pos = atomicAdd(&cnt[pe[kk]], 1);
            tlist[pe[kk] * NB + pos] = b;
            plist[pe[kk] * NB + pos] = p;
        }
    }
}

// ---------------- grouped gathered GEMM: out += p * (x @ W_e^T + b_e) ----------------
// PRE=1: bf16 pre-converted inputs (16B copy staging). PRE=0: fp32 + in-loop cvt (fallback).
template <int PRE>
__global__ __launch_bounds__(256) void k_gemm(
    const void* __restrict__ xa, const void* __restrict__ wa,
    const float* __restrict__ b_e, const int* __restrict__ cnt,
    const int* __restrict__ tlist, const float* __restrict__ plist,
    float* __restrict__ out)
{
    const int e     = blockIdx.z;
    const int count = cnt[e];
    const int mt    = blockIdx.y;
    if (mt * BM >= count) return;
    const int nt   = blockIdx.x;
    const int tid  = threadIdx.x;
    const int lane = tid & 63;
    const int w    = tid >> 6;
    const int wm = w >> 1, wn = w & 1;       // 2x2 waves, 64x64 each
    const int fr = lane & 15, fq = lane >> 4;

    __shared__ short As[BM][LDA];
    __shared__ short Bs[BM][LDA];
    const int* tl = tlist + e * NB;

    f4_t acc[4][4];
#pragma unroll
    for (int i = 0; i < 4; ++i)
#pragma unroll
        for (int j = 0; j < 4; ++j) acc[i][j] = {0.f, 0.f, 0.f, 0.f};

    auto mfma_tile = [&]() {
#pragma unroll
        for (int kk = 0; kk < 2; ++kk) {
            bf8_t af[4], bfr[4];
#pragma unroll
            for (int m = 0; m < 4; ++m)
                af[m] = *(const bf8_t*)&As[wm * 64 + m * 16 + fr][kk * 32 + fq * 8];
#pragma unroll
            for (int n = 0; n < 4; ++n)
                bfr[n] = *(const bf8_t*)&Bs[wn * 64 + n * 16 + fr][kk * 32 + fq * 8];
#pragma unroll
            for (int m = 0; m < 4; ++m)
#pragma unroll
                for (int n = 0; n < 4; ++n)
                    acc[m][n] = __builtin_amdgcn_mfma_f32_16x16x32_bf16(af[m], bfr[n], acc[m][n], 0, 0, 0);
        }
    };

    if (PRE) {
        const ushort* xb = (const ushort*)xa;
        const ushort* wb = (const ushort*)wa + (size_t)e * NHO * NHI + (size_t)(nt * BN) * NHI;
        const int col8 = tid & 7;            // 16B chunk along K
        const int r0   = tid >> 3;           // 0..31
        int tokr[4];
#pragma unroll
        for (int rr = 0; rr < 4; ++rr)
            tokr[rr] = tl[min(mt * BM + r0 + rr * 32, count - 1)];
        for (int k0 = 0; k0 < NHI; k0 += BK) {
#pragma unroll
            for (int rr = 0; rr < 4; ++rr) {
                int r = r0 + rr * 32;
                *(bf8_t*)&As[r][col8 * 8] =
                    *(const bf8_t*)(xb + (size_t)tokr[rr] * NHI + k0 + col8 * 8);
                *(bf8_t*)&Bs[r][col8 * 8] =
                    *(const bf8_t*)(wb + (size_t)r * NHI + k0 + col8 * 8);
            }
            __syncthreads();
            mfma_tile();
            __syncthreads();
        }
    } else {
        const float* xf = (const float*)xa;
        const float* wb = (const float*)wa + (size_t)e * NHO * NHI + (size_t)(nt * BN) * NHI;
        const int col4 = tid & 15;
        const int r0   = tid >> 4;
        int tokr[8];
#pragma unroll
        for (int rr = 0; rr < 8; ++rr)
            tokr[rr] = tl[min(mt * BM + r0 + rr * 16, count - 1)];
        for (int k0 = 0; k0 < NHI; k0 += BK) {
#pragma unroll
            for (int rr = 0; rr < 8; ++rr) {
                int r = r0 + rr * 16;
                float4 av = *(const float4*)(xf + (size_t)tokr[rr] * NHI + k0 + col4 * 4);
                uint2 ap; ap.x = f2b(av.x) | (f2b(av.y) << 16); ap.y = f2b(av.z) | (f2b(av.w) << 16);
                *(uint2*)&As[r][col4 * 4] = ap;
                float4 wv = *(const float4*)(wb + (size_t)r * NHI + k0 + col4 * 4);
                uint2 wp; wp.x = f2b(wv.x) | (f2b(wv.y) << 16); wp.y = f2b(wv.z) | (f2b(wv.w) << 16);
                *(uint2*)&Bs[r][col4 * 4] = wp;
            }
            __syncthreads();
            mfma_tile();
            __syncthreads();
        }
    }

    // epilogue: out[tok, o] += p * (acc + b_e[e, o])   (validated in round 9)
    const float* be = b_e + e * NHO;
    float bias[4];
#pragma unroll
    for (int n = 0; n < 4; ++n) bias[n] = be[nt * BN + wn * 64 + n * 16 + fr];
    const float* pl = plist + e * NB;
#pragma unroll
    for (int m = 0; m < 4; ++m) {
#pragma unroll
        for (int ri = 0; ri < 4; ++ri) {
            int g = mt * BM + wm * 64 + m * 16 + fq * 4 + ri;
            if (g < count) {
                int tok = tl[g];
                float p = pl[g];
                float* orow = out + (size_t)tok * NHO + nt * BN + wn * 64;
#pragma unroll
                for (int n = 0; n < 4; ++n)
                    atomicAdd(orow + n * 16 + fr, p * (acc[m][n][ri] + bias[n]));
            }
        }
    }
}

// ---------------- finalize: frac_prob + load balance loss ----------------
__global__ void k_fin(const int* __restrict__ selc, const float* __restrict__ psum,
                      float* __restrict__ tail)
{
    int t = threadIdx.x;
    if (t < NE) tail[t] = psum[t] * (1.f / NB);
    if (t == 0) {
        float l = 0.f;
        for (int e2 = 0; e2 < NE; ++e2)
            l += ((float)selc[e2] * (1.f / NB)) * (psum[e2] * (1.f / NB));
        tail[NE] = (float)NE * l;
    }
}

extern "C" void kernel_launch(void* const* d_in, const int* in_sizes, int n_in,
                              void* d_out, int out_size, void* d_ws, size_t ws_size,
                              hipStream_t stream)
{
    const float* x   = (const float*)d_in[0];
    const float* W_e = (const float*)d_in[1];
    const float* b_e = (const float*)d_in[2];
    const float* W_r = (const float*)d_in[3];
    const float* b_r = (const float*)d_in[4];
    float* out = (float*)d_out;

    char* ws = (char*)d_ws;
    size_t off = 0;
    int*   cnt   = (int*)(ws);
    int*   selc  = (int*)(ws + 64);
    float* psum  = (float*)(ws + 128);
    off = 256;
    int*   tlist = (int*)(ws + off); off += 4ull * NE * NB;
    float* plist = (float*)(ws + off); off += 4ull * NE * NB;
    uint32_t* xb  = (uint32_t*)(ws + off); off += 2ull * NB * NHI;
    uint32_t* web = (uint32_t*)(ws + off); off += 2ull * NE * NHO * NHI;
    const bool pre = (ws_size >= off);

    hipMemsetAsync(d_out, 0, sizeof(float) * (size_t)NB * NHO, stream);
    hipMemsetAsync(ws, 0, 256, stream);
    if (pre) {
        k_cvt<<<dim3(NB * NHI / 8 / 256), dim3(256), 0, stream>>>(x, xb, NB * NHI / 8);
        k_cvt<<<dim3(NE * NHO * NHI / 8 / 256), dim3(256), 0, stream>>>(W_e, web, NE * NHO * NHI / 8);
    }
    k_router<<<dim3(NB / 16), dim3(256), 0, stream>>>(x, W_r, b_r, cnt, psum, selc, tlist, plist);
    if (pre)
        k_gemm<1><<<dim3(NHO / BN, NB / BM, NE), dim3(256), 0, stream>>>(
            (const void*)xb, (const void*)web, b_e, cnt, tlist, plist, out);
    else
        k_gemm<0><<<dim3(NHO / BN, NB / BM, NE), dim3(256), 0, stream>>>(
            (const void*)x, (const void*)W_e, b_e, cnt, tlist, plist, out);
    k_fin<<<dim3(1), dim3(64), 0, stream>>>(selc, psum, out + (size_t)NB * NHO);
}